// Round 1
// baseline (4629.607 us; speedup 1.0000x reference)
//
#include <hip/hip_runtime.h>

#define B_ 8
#define H_ 128
#define W_ 256
#define C_ 64
#define F_ 64
#define DILX 2

// ---------------------------------------------------------------------------
// Fused q/k/v dilated 3x3 conv (dil=2, SAME). One block per (b,h), 256
// threads = 256 w positions. Each thread accumulates all 3*64 output
// features in VGPRs. X staged in LDS in c-chunks of 16 (3 rows x 260 w x 16c
// = 49.9 KB). Weights are wave-uniform -> scalar loads -> v_fmac(v,s,v).
// ---------------------------------------------------------------------------
__global__ __launch_bounds__(256, 2) void qkv_conv_kernel(
    const float* __restrict__ X,
    const float* __restrict__ Wq, const float* __restrict__ bq,
    const float* __restrict__ Wk, const float* __restrict__ bk,
    const float* __restrict__ Wv, const float* __restrict__ bv,
    float* __restrict__ Qo, float* __restrict__ Ko, float* __restrict__ Vo)
{
    __shared__ float Xs[3 * 260 * 16];

    const int tid = threadIdx.x;          // = w
    const int bh  = blockIdx.x;
    const int b   = bh >> 7;              // H_=128
    const int h   = bh & 127;

    float accq[64], acck[64], accv[64];
    #pragma unroll
    for (int f = 0; f < 64; ++f) { accq[f] = 0.f; acck[f] = 0.f; accv[f] = 0.f; }

    for (int c0 = 0; c0 < C_; c0 += 16) {
        __syncthreads();   // protect previous chunk's reads
        // ---- stage X rows {h-2, h, h+2}, w in [-2, 257], 16 channels ----
        for (int e = tid; e < 3 * 260 * 4; e += 256) {
            const int r   = e / (260 * 4);
            const int rem = e - r * (260 * 4);
            const int wp  = rem >> 2;
            const int c4  = rem & 3;
            const int ih  = h + (r - 1) * DILX;
            const int iw  = wp - 2;
            float4 val = make_float4(0.f, 0.f, 0.f, 0.f);
            if ((unsigned)ih < (unsigned)H_ && (unsigned)iw < (unsigned)W_) {
                val = *(const float4*)(X + (((long)(b * H_ + ih) * W_ + iw) * C_ + c0 + c4 * 4));
            }
            *(float4*)(&Xs[(r * 260 + wp) * 16 + c4 * 4]) = val;
        }
        __syncthreads();

        // ---- accumulate ----
        #pragma unroll 1
        for (int kh = 0; kh < 3; ++kh) {
            #pragma unroll 1
            for (int kw = 0; kw < 3; ++kw) {
                const float* Xrow = &Xs[(kh * 260 + tid + kw * 2) * 16];
                const int wb0 = ((kh * 3 + kw) * C_ + c0) * F_;
                #pragma unroll 4
                for (int c = 0; c < 16; ++c) {
                    const float x = Xrow[c];
                    const float* wq = Wq + wb0 + c * F_;
                    const float* wk = Wk + wb0 + c * F_;
                    const float* wv = Wv + wb0 + c * F_;
                    #pragma unroll
                    for (int f = 0; f < 64; ++f) accq[f] = fmaf(x, wq[f], accq[f]);
                    #pragma unroll
                    for (int f = 0; f < 64; ++f) acck[f] = fmaf(x, wk[f], acck[f]);
                    #pragma unroll
                    for (int f = 0; f < 64; ++f) accv[f] = fmaf(x, wv[f], accv[f]);
                }
            }
        }
    }

    // ---- bias + store (per-thread contiguous 64 floats, float4 stores) ----
    const long obase = ((long)bh * W_ + tid) * F_;
    #pragma unroll
    for (int f4 = 0; f4 < 16; ++f4) {
        float4 oq, ok, ov;
        oq.x = accq[f4*4+0] + bq[f4*4+0];
        oq.y = accq[f4*4+1] + bq[f4*4+1];
        oq.z = accq[f4*4+2] + bq[f4*4+2];
        oq.w = accq[f4*4+3] + bq[f4*4+3];
        ok.x = acck[f4*4+0] + bk[f4*4+0];
        ok.y = acck[f4*4+1] + bk[f4*4+1];
        ok.z = acck[f4*4+2] + bk[f4*4+2];
        ok.w = acck[f4*4+3] + bk[f4*4+3];
        ov.x = accv[f4*4+0] + bv[f4*4+0];
        ov.y = accv[f4*4+1] + bv[f4*4+1];
        ov.z = accv[f4*4+2] + bv[f4*4+2];
        ov.w = accv[f4*4+3] + bv[f4*4+3];
        *(float4*)(Qo + obase + f4*4) = oq;
        *(float4*)(Ko + obase + f4*4) = ok;
        *(float4*)(Vo + obase + f4*4) = ov;
    }
}

// ---------------------------------------------------------------------------
// Flash-style attention along W per (b,h). One block per (b,h), 256 threads
// = 256 q rows. K/V staged in LDS tiles of 32 rows (16 KB). Online softmax.
// ---------------------------------------------------------------------------
#define TK 32

__global__ __launch_bounds__(256, 2) void attn_kernel(
    const float* __restrict__ Q, const float* __restrict__ Kk,
    const float* __restrict__ V, float* __restrict__ Out)
{
    __shared__ float Ks[TK * 64];
    __shared__ float Vs[TK * 64];

    const int tid = threadIdx.x;          // = q row
    const long bh = blockIdx.x;
    const float* Qb = Q  + bh * W_ * F_;
    const float* Kb = Kk + bh * W_ * F_;
    const float* Vb = V  + bh * W_ * F_;

    float q[64];
    #pragma unroll
    for (int f4 = 0; f4 < 16; ++f4) {
        float4 t = *(const float4*)(Qb + (long)tid * F_ + f4 * 4);
        q[f4*4+0] = t.x; q[f4*4+1] = t.y; q[f4*4+2] = t.z; q[f4*4+3] = t.w;
    }

    float acc[64];
    #pragma unroll
    for (int f = 0; f < 64; ++f) acc[f] = 0.f;
    float m = -3.0e38f, l = 0.f;

    for (int t0 = 0; t0 < W_; t0 += TK) {
        __syncthreads();
        // stage K,V tile (TK*64 floats = TK*16 float4 each)
        for (int e = tid; e < TK * 16; e += 256) {
            ((float4*)Ks)[e] = ((const float4*)(Kb + (long)t0 * F_))[e];
            ((float4*)Vs)[e] = ((const float4*)(Vb + (long)t0 * F_))[e];
        }
        __syncthreads();

        float s[TK];
        #pragma unroll 4
        for (int j = 0; j < TK; ++j) {
            float sj = 0.f;
            const float* kr = &Ks[j * 64];
            #pragma unroll
            for (int f4 = 0; f4 < 16; ++f4) {
                float4 kv = *(const float4*)(kr + f4 * 4);
                sj = fmaf(q[f4*4+0], kv.x, sj);
                sj = fmaf(q[f4*4+1], kv.y, sj);
                sj = fmaf(q[f4*4+2], kv.z, sj);
                sj = fmaf(q[f4*4+3], kv.w, sj);
            }
            s[j] = sj;
        }

        float tmax = s[0];
        #pragma unroll
        for (int j = 1; j < TK; ++j) tmax = fmaxf(tmax, s[j]);
        const float mnew = fmaxf(m, tmax);
        const float alpha = __expf(m - mnew);
        l *= alpha;
        #pragma unroll
        for (int f = 0; f < 64; ++f) acc[f] *= alpha;

        #pragma unroll 4
        for (int j = 0; j < TK; ++j) {
            const float p = __expf(s[j] - mnew);
            l += p;
            const float* vr = &Vs[j * 64];
            #pragma unroll
            for (int f4 = 0; f4 < 16; ++f4) {
                float4 vv = *(const float4*)(vr + f4 * 4);
                acc[f4*4+0] = fmaf(p, vv.x, acc[f4*4+0]);
                acc[f4*4+1] = fmaf(p, vv.y, acc[f4*4+1]);
                acc[f4*4+2] = fmaf(p, vv.z, acc[f4*4+2]);
                acc[f4*4+3] = fmaf(p, vv.w, acc[f4*4+3]);
            }
        }
        m = mnew;
    }

    const float inv_l = 1.f / l;
    const long ob = (bh * W_ + tid) * F_;
    #pragma unroll
    for (int f4 = 0; f4 < 16; ++f4) {
        float4 o;
        o.x = acc[f4*4+0] * inv_l;
        o.y = acc[f4*4+1] * inv_l;
        o.z = acc[f4*4+2] * inv_l;
        o.w = acc[f4*4+3] * inv_l;
        *(float4*)(Out + ob + f4*4) = o;
    }
}

extern "C" void kernel_launch(void* const* d_in, const int* in_sizes, int n_in,
                              void* d_out, int out_size, void* d_ws, size_t ws_size,
                              hipStream_t stream) {
    const float* X  = (const float*)d_in[0];
    const float* Wq = (const float*)d_in[1];
    const float* bq = (const float*)d_in[2];
    const float* Wk = (const float*)d_in[3];
    const float* bk = (const float*)d_in[4];
    const float* Wv = (const float*)d_in[5];
    const float* bv = (const float*)d_in[6];
    float* out = (float*)d_out;

    const size_t nelem = (size_t)B_ * H_ * W_ * F_;   // 16,777,216
    float* q = (float*)d_ws;
    float* k = q + nelem;
    float* v = k + nelem;

    qkv_conv_kernel<<<B_ * H_, 256, 0, stream>>>(X, Wq, bq, Wk, bk, Wv, bv, q, k, v);
    attn_kernel<<<B_ * H_, 256, 0, stream>>>(q, k, v, out);
}

// Round 3
// 1233.722 us; speedup vs baseline: 3.7526x; 3.7526x over previous
//
#include <hip/hip_runtime.h>

#define B_ 8
#define H_ 128
#define W_ 256
#define C_ 64
#define F_ 64
#define DILX 2
#define CC 8          // channel chunk

// ---------------------------------------------------------------------------
// Fused q/k/v dilated 3x3 conv (dil=2, SAME), GEMM-style.
// Grid: 1024 (b,h) x 2 f-halves. Block 256 threads = 32 w-groups x 8 f-groups.
// Each thread: 8 w x 12 f fp32 accumulators (96).
// Per (kh, c-chunk): stage X row transposed [c][w] (conflict-free b128 reads)
// and weights [kw][c][96] in LDS; inner loop = 13 LDS b128 reads : 288 FMA.
// ---------------------------------------------------------------------------
__global__ __launch_bounds__(256, 3) void qkv_conv_kernel(
    const float* __restrict__ X,
    const float* __restrict__ Wq, const float* __restrict__ bq,
    const float* __restrict__ Wk, const float* __restrict__ bk,
    const float* __restrict__ Wv, const float* __restrict__ bv,
    float* __restrict__ Qo, float* __restrict__ Ko, float* __restrict__ Vo)
{
    __shared__ float Xs[CC * 264];       // [c][w+4], w in [-2,257] -> idx [2,261]
    __shared__ float Ws[3 * CC * 96];    // [kw][c][f']

    const int tid  = threadIdx.x;
    const int tw   = tid >> 3;           // w-group [0,32)
    const int tn   = tid & 7;            // f-group [0,8)
    const int bx   = blockIdx.x;
    const int bh   = bx >> 1;
    const int half = bx & 1;
    const int b    = bh >> 7;
    const int h    = bh & 127;

    float acc[96];
    #pragma unroll
    for (int i = 0; i < 96; ++i) acc[i] = 0.f;

    for (int kh = 0; kh < 3; ++kh) {
        const int ih = h + (kh - 1) * DILX;
        if ((unsigned)ih >= (unsigned)H_) continue;
        const float* Xrow = X + ((long)(b * H_ + ih) * W_) * C_;

        for (int c0 = 0; c0 < C_; c0 += CC) {
            __syncthreads();   // protect previous chunk's reads

            // ---- stage X transposed: Xs[c][w+4] for w in [-2,257] ----
            {
                const int w = tid - 2;   // [-2, 253]
                float4 v0 = make_float4(0.f,0.f,0.f,0.f);
                float4 v1 = make_float4(0.f,0.f,0.f,0.f);
                if ((unsigned)w < (unsigned)W_) {
                    v0 = *(const float4*)(Xrow + (long)w * C_ + c0);
                    v1 = *(const float4*)(Xrow + (long)w * C_ + c0 + 4);
                }
                const int iw = w + 4;
                Xs[0*264 + iw] = v0.x; Xs[1*264 + iw] = v0.y;
                Xs[2*264 + iw] = v0.z; Xs[3*264 + iw] = v0.w;
                Xs[4*264 + iw] = v1.x; Xs[5*264 + iw] = v1.y;
                Xs[6*264 + iw] = v1.z; Xs[7*264 + iw] = v1.w;
                if (tid < 4) {
                    const int w2 = 254 + tid;   // [254,257]
                    float4 u0 = make_float4(0.f,0.f,0.f,0.f);
                    float4 u1 = make_float4(0.f,0.f,0.f,0.f);
                    if (w2 < W_) {
                        u0 = *(const float4*)(Xrow + (long)w2 * C_ + c0);
                        u1 = *(const float4*)(Xrow + (long)w2 * C_ + c0 + 4);
                    }
                    const int iw2 = w2 + 4;
                    Xs[0*264 + iw2] = u0.x; Xs[1*264 + iw2] = u0.y;
                    Xs[2*264 + iw2] = u0.z; Xs[3*264 + iw2] = u0.w;
                    Xs[4*264 + iw2] = u1.x; Xs[5*264 + iw2] = u1.y;
                    Xs[6*264 + iw2] = u1.z; Xs[7*264 + iw2] = u1.w;
                }
            }

            // ---- stage weights: Ws[kw][c][f'], f' = half*96 + [0,96) ----
            for (int e = tid; e < 3 * CC * 96; e += 256) {
                const int f    = e % 96;
                const int rest = e / 96;
                const int c    = rest % CC;
                const int kw   = rest / CC;
                const int F    = half * 96 + f;
                const float* src; int ff;
                if (F < 64)       { src = Wq; ff = F;       }
                else if (F < 128) { src = Wk; ff = F - 64;  }
                else              { src = Wv; ff = F - 128; }
                Ws[(kw * CC + c) * 96 + f] =
                    src[((kh * 3 + kw) * C_ + (c0 + c)) * F_ + ff];
            }
            __syncthreads();

            // ---- compute: 8 c x (4 + 9 b128 reads, 288 fma) ----
            #pragma unroll 2
            for (int c = 0; c < CC; ++c) {
                const float* xr = &Xs[c * 264 + tw * 8];
                float xw[16];
                {
                    float4 a0 = *(const float4*)(xr);
                    float4 a1 = *(const float4*)(xr + 4);
                    float4 a2 = *(const float4*)(xr + 8);
                    float4 a3 = *(const float4*)(xr + 12);
                    xw[0]=a0.x; xw[1]=a0.y; xw[2]=a0.z; xw[3]=a0.w;
                    xw[4]=a1.x; xw[5]=a1.y; xw[6]=a1.z; xw[7]=a1.w;
                    xw[8]=a2.x; xw[9]=a2.y; xw[10]=a2.z; xw[11]=a2.w;
                    xw[12]=a3.x; xw[13]=a3.y; xw[14]=a3.z; xw[15]=a3.w;
                }
                #pragma unroll
                for (int kw = 0; kw < 3; ++kw) {
                    const float* wr = &Ws[(kw * CC + c) * 96 + tn * 12];
                    float wt[12];
                    {
                        float4 w0 = *(const float4*)(wr);
                        float4 w1 = *(const float4*)(wr + 4);
                        float4 w2 = *(const float4*)(wr + 8);
                        wt[0]=w0.x; wt[1]=w0.y; wt[2]=w0.z; wt[3]=w0.w;
                        wt[4]=w1.x; wt[5]=w1.y; wt[6]=w1.z; wt[7]=w1.w;
                        wt[8]=w2.x; wt[9]=w2.y; wt[10]=w2.z; wt[11]=w2.w;
                    }
                    #pragma unroll
                    for (int i = 0; i < 8; ++i) {
                        const float x = xw[i + 2 * kw + 2];
                        #pragma unroll
                        for (int fi = 0; fi < 12; ++fi)
                            acc[i * 12 + fi] = fmaf(x, wt[fi], acc[i * 12 + fi]);
                    }
                }
            }
        }
    }

    // ---- epilogue: bias + store ----
    float bias[12];
    #pragma unroll
    for (int fi = 0; fi < 12; ++fi) {
        const int F = half * 96 + tn * 12 + fi;
        bias[fi] = (F < 64) ? bq[F] : (F < 128) ? bk[F - 64] : bv[F - 128];
    }
    #pragma unroll
    for (int i = 0; i < 8; ++i) {
        const int w = tw * 8 + i;
        const long rowbase = ((long)bh * W_ + w) * F_;
        #pragma unroll
        for (int q4 = 0; q4 < 3; ++q4) {
            const int F = half * 96 + tn * 12 + q4 * 4;
            float* dst; int ff;
            if (F < 64)       { dst = Qo; ff = F;       }
            else if (F < 128) { dst = Ko; ff = F - 64;  }
            else              { dst = Vo; ff = F - 128; }
            float4 o;
            o.x = acc[i * 12 + q4 * 4 + 0] + bias[q4 * 4 + 0];
            o.y = acc[i * 12 + q4 * 4 + 1] + bias[q4 * 4 + 1];
            o.z = acc[i * 12 + q4 * 4 + 2] + bias[q4 * 4 + 2];
            o.w = acc[i * 12 + q4 * 4 + 3] + bias[q4 * 4 + 3];
            *(float4*)(dst + rowbase + ff) = o;
        }
    }
}

// ---------------------------------------------------------------------------
// Flash-style attention along W per (b,h). One block per (b,h), 256 threads
// = 256 q rows. K/V staged in LDS tiles of 32 rows (16 KB). Online softmax.
// ---------------------------------------------------------------------------
#define TK 32

__global__ __launch_bounds__(256, 2) void attn_kernel(
    const float* __restrict__ Q, const float* __restrict__ Kk,
    const float* __restrict__ V, float* __restrict__ Out)
{
    __shared__ float Ks[TK * 64];
    __shared__ float Vs[TK * 64];

    const int tid = threadIdx.x;          // = q row
    const long bh = blockIdx.x;
    const float* Qb = Q  + bh * W_ * F_;
    const float* Kb = Kk + bh * W_ * F_;
    const float* Vb = V  + bh * W_ * F_;

    float q[64];
    #pragma unroll
    for (int f4 = 0; f4 < 16; ++f4) {
        float4 t = *(const float4*)(Qb + (long)tid * F_ + f4 * 4);
        q[f4*4+0] = t.x; q[f4*4+1] = t.y; q[f4*4+2] = t.z; q[f4*4+3] = t.w;
    }

    float acc[64];
    #pragma unroll
    for (int f = 0; f < 64; ++f) acc[f] = 0.f;
    float m = -3.0e38f, l = 0.f;

    for (int t0 = 0; t0 < W_; t0 += TK) {
        __syncthreads();
        for (int e = tid; e < TK * 16; e += 256) {
            ((float4*)Ks)[e] = ((const float4*)(Kb + (long)t0 * F_))[e];
            ((float4*)Vs)[e] = ((const float4*)(Vb + (long)t0 * F_))[e];
        }
        __syncthreads();

        float s[TK];
        #pragma unroll 4
        for (int j = 0; j < TK; ++j) {
            float sj = 0.f;
            const float* kr = &Ks[j * 64];
            #pragma unroll
            for (int f4 = 0; f4 < 16; ++f4) {
                float4 kv = *(const float4*)(kr + f4 * 4);
                sj = fmaf(q[f4*4+0], kv.x, sj);
                sj = fmaf(q[f4*4+1], kv.y, sj);
                sj = fmaf(q[f4*4+2], kv.z, sj);
                sj = fmaf(q[f4*4+3], kv.w, sj);
            }
            s[j] = sj;
        }

        float tmax = s[0];
        #pragma unroll
        for (int j = 1; j < TK; ++j) tmax = fmaxf(tmax, s[j]);
        const float mnew = fmaxf(m, tmax);
        const float alpha = __expf(m - mnew);
        l *= alpha;
        #pragma unroll
        for (int f = 0; f < 64; ++f) acc[f] *= alpha;

        #pragma unroll 4
        for (int j = 0; j < TK; ++j) {
            const float p = __expf(s[j] - mnew);
            l += p;
            const float* vr = &Vs[j * 64];
            #pragma unroll
            for (int f4 = 0; f4 < 16; ++f4) {
                float4 vv = *(const float4*)(vr + f4 * 4);
                acc[f4*4+0] = fmaf(p, vv.x, acc[f4*4+0]);
                acc[f4*4+1] = fmaf(p, vv.y, acc[f4*4+1]);
                acc[f4*4+2] = fmaf(p, vv.z, acc[f4*4+2]);
                acc[f4*4+3] = fmaf(p, vv.w, acc[f4*4+3]);
            }
        }
        m = mnew;
    }

    const float inv_l = 1.f / l;
    const long ob = (bh * W_ + tid) * F_;
    #pragma unroll
    for (int f4 = 0; f4 < 16; ++f4) {
        float4 o;
        o.x = acc[f4*4+0] * inv_l;
        o.y = acc[f4*4+1] * inv_l;
        o.z = acc[f4*4+2] * inv_l;
        o.w = acc[f4*4+3] * inv_l;
        *(float4*)(Out + ob + f4*4) = o;
    }
}

extern "C" void kernel_launch(void* const* d_in, const int* in_sizes, int n_in,
                              void* d_out, int out_size, void* d_ws, size_t ws_size,
                              hipStream_t stream) {
    const float* X  = (const float*)d_in[0];
    const float* Wq = (const float*)d_in[1];
    const float* bq = (const float*)d_in[2];
    const float* Wk = (const float*)d_in[3];
    const float* bk = (const float*)d_in[4];
    const float* Wv = (const float*)d_in[5];
    const float* bv = (const float*)d_in[6];
    float* out = (float*)d_out;

    const size_t nelem = (size_t)B_ * H_ * W_ * F_;   // 16,777,216
    float* q = (float*)d_ws;
    float* k = q + nelem;
    float* v = k + nelem;

    qkv_conv_kernel<<<B_ * H_ * 2, 256, 0, stream>>>(X, Wq, bq, Wk, bk, Wv, bv, q, k, v);
    attn_kernel<<<B_ * H_, 256, 0, stream>>>(q, k, v, out);
}

// Round 5
// 344.315 us; speedup vs baseline: 13.4458x; 3.5831x over previous
//
#include <hip/hip_runtime.h>

#define B_ 8
#define H_ 128
#define W_ 256
#define C_ 64
#define F_ 64

typedef __attribute__((ext_vector_type(8))) short short8;
typedef __attribute__((ext_vector_type(8))) _Float16 half8;
typedef __attribute__((ext_vector_type(4))) float f32x4;

__device__ __forceinline__ unsigned short f2h(float x) {
    _Float16 h = (_Float16)x;                  // v_cvt_f16_f32, RTN
    return __builtin_bit_cast(unsigned short, h);
}

__device__ __forceinline__ f32x4 mfma16(short8 a, short8 b, f32x4 c) {
    return __builtin_amdgcn_mfma_f32_16x16x32_f16(
        __builtin_bit_cast(half8, a), __builtin_bit_cast(half8, b), c, 0, 0, 0);
}

// ---------------------------------------------------------------------------
// Pre-kernel: transpose+convert weights to fp16  Wt[tap(9)][f(192)][c(64)],
// f = 0..63 Wq, 64..127 Wk, 128..191 Wv.   9*192*64 = 110592 elems.
// ---------------------------------------------------------------------------
__global__ void wprep_kernel(const float* __restrict__ Wq,
                             const float* __restrict__ Wk,
                             const float* __restrict__ Wv,
                             unsigned short* __restrict__ Wt)
{
    int e = blockIdx.x * 256 + threadIdx.x;           // < 110592
    int c   = e & 63;
    int f   = (e >> 6) % 192;
    int tap = e / 12288;
    const float* src = (f < 64) ? Wq : (f < 128) ? Wk : Wv;
    int ff = f & 63;
    float v = src[(long)tap * 4096 + c * 64 + ff];    // W[tap][c][F]
    Wt[e] = f2h(v);
}

// ---------------------------------------------------------------------------
// Fused q/k/v dilated 3x3 conv (dil=2, SAME) via fp16 MFMA.
// Grid: 1024 (b,h) x 2 f-halves (96 f each). 256 thr = 4 waves.
// Wave w-range 64 (4 m-tiles of 16). n: 6 tiles of 16. K per (kh,kw) = 64 c.
// LDS rows padded to 144B (bank-floor for b128 frag reads).
// Outputs: Q,K fp16 [bh][w][f] (w-major), V fp16 [bh][f][w] (f-major).
// ---------------------------------------------------------------------------
#define XST 72   // Xs row stride in shorts (144 B)
#define WST 72   // Wls row stride

__global__ __launch_bounds__(256, 2) void conv_mfma(
    const float* __restrict__ X, const unsigned short* __restrict__ Wt,
    const float* __restrict__ bq, const float* __restrict__ bk,
    const float* __restrict__ bv,
    unsigned short* __restrict__ Qg, unsigned short* __restrict__ Kg,
    unsigned short* __restrict__ Vtg)
{
    __shared__ __align__(16) unsigned short Xs[260 * XST];   // [w+2][c]
    __shared__ __align__(16) unsigned short Wls[288 * WST];  // [kw*96+f][c]

    const int tid  = threadIdx.x;
    const int wv   = tid >> 6;
    const int lane = tid & 63;
    const int l15  = lane & 15;
    const int g    = lane >> 4;
    const int bx   = blockIdx.x;
    const int bh   = bx >> 1;
    const int half = bx & 1;
    const int b    = bh >> 7;
    const int h    = bh & 127;

    f32x4 acc[4][6];
    #pragma unroll
    for (int mt = 0; mt < 4; ++mt)
        #pragma unroll
        for (int nt = 0; nt < 6; ++nt)
            acc[mt][nt] = (f32x4){0.f, 0.f, 0.f, 0.f};

    for (int kh = 0; kh < 3; ++kh) {
        const int ih = h + 2 * (kh - 1);
        if ((unsigned)ih >= (unsigned)H_) continue;     // uniform per block
        const float* Xr = X + ((long)(b * H_ + ih) * W_) * C_;

        __syncthreads();   // protect previous iteration's reads

        // ---- stage X row: rows 0..259 = input w -2..257, 64 c each ----
        for (int e = tid; e < 260 * 16; e += 256) {
            const int row = e >> 4, c4 = e & 15;
            const int w_in = row - 2;
            float4 val = make_float4(0.f, 0.f, 0.f, 0.f);
            if ((unsigned)w_in < (unsigned)W_)
                val = *(const float4*)(Xr + (long)w_in * 64 + c4 * 4);
            uint2 p;
            p.x = (unsigned)f2h(val.x) | ((unsigned)f2h(val.y) << 16);
            p.y = (unsigned)f2h(val.z) | ((unsigned)f2h(val.w) << 16);
            *(uint2*)(Xs + row * XST + c4 * 4) = p;
        }
        // ---- stage weights: [kw][f 96][c 64] for this half ----
        for (int e = tid; e < 2304; e += 256) {
            const int c8 = e & 7, f = (e >> 3) % 96, kw = e / 768;
            uint4 d = *(const uint4*)(Wt +
                (((long)(kh * 3 + kw) * 192 + half * 96 + f) * 64 + c8 * 8));
            *(uint4*)(Wls + (kw * 96 + f) * WST + c8 * 8) = d;
        }
        __syncthreads();

        #pragma unroll
        for (int kw = 0; kw < 3; ++kw) {
            short8 bfrag[6][2];
            #pragma unroll
            for (int nt = 0; nt < 6; ++nt)
                #pragma unroll
                for (int kt = 0; kt < 2; ++kt)
                    bfrag[nt][kt] = *(const short8*)(Wls +
                        (kw * 96 + nt * 16 + l15) * WST + (kt * 4 + g) * 8);
            #pragma unroll
            for (int kt = 0; kt < 2; ++kt)
                #pragma unroll
                for (int mt = 0; mt < 4; ++mt) {
                    const int row = wv * 64 + mt * 16 + l15 + 2 * kw;
                    short8 a = *(const short8*)(Xs + row * XST + (kt * 4 + g) * 8);
                    #pragma unroll
                    for (int nt = 0; nt < 6; ++nt)
                        acc[mt][nt] = mfma16(a, bfrag[nt][kt], acc[mt][nt]);
                }
        }
    }

    // ---- epilogue: bias + store fp16 ----
    float bias[6];
    #pragma unroll
    for (int nt = 0; nt < 6; ++nt) {
        const int fp = half * 96 + nt * 16 + l15;
        bias[nt] = (fp < 64) ? bq[fp] : (fp < 128) ? bk[fp - 64] : bv[fp - 128];
    }
    #pragma unroll
    for (int mt = 0; mt < 4; ++mt) {
        const int wrow = wv * 64 + mt * 16 + 4 * g;
        #pragma unroll
        for (int nt = 0; nt < 6; ++nt) {
            const int fp = half * 96 + nt * 16 + l15;
            if (fp < 128) {   // Q or K: [bh][w][f] 2B stores (32B runs)
                unsigned short* dst = (fp < 64) ? Qg : Kg;
                const int f = fp & 63;
                #pragma unroll
                for (int r = 0; r < 4; ++r)
                    dst[((long)bh * 256 + wrow + r) * 64 + f] =
                        f2h(acc[mt][nt][r] + bias[nt]);
            } else {          // V transposed: [bh][f][w], 4 consecutive w -> b64
                const int f = fp - 128;
                uint2 p;
                p.x = (unsigned)f2h(acc[mt][nt][0] + bias[nt]) |
                      ((unsigned)f2h(acc[mt][nt][1] + bias[nt]) << 16);
                p.y = (unsigned)f2h(acc[mt][nt][2] + bias[nt]) |
                      ((unsigned)f2h(acc[mt][nt][3] + bias[nt]) << 16);
                *(uint2*)(Vtg + ((long)bh * 64 + f) * 256 + wrow) = p;
            }
        }
    }
}

// ---------------------------------------------------------------------------
// Flash attention along W per (b,h) via fp16 MFMA. 256 thr = 4 waves,
// wave owns 64 q-rows. kv tiles of 32. Online softmax, P wave-private in LDS.
// ---------------------------------------------------------------------------
#define QST 72   // Qs/Ks row stride (shorts)
#define PST 40   // Ps/Vts row stride (80 B)

__global__ __launch_bounds__(256, 2) void attn_mfma(
    const unsigned short* __restrict__ Qg, const unsigned short* __restrict__ Kg,
    const unsigned short* __restrict__ Vtg, float* __restrict__ Out)
{
    __shared__ __align__(16) unsigned short Qs[256 * QST];
    __shared__ __align__(16) unsigned short Ks[32 * QST];
    __shared__ __align__(16) unsigned short Vts[64 * PST];
    __shared__ __align__(16) unsigned short Ps[4][64 * PST];

    const int tid  = threadIdx.x;
    const int wv   = tid >> 6;
    const int lane = tid & 63;
    const int l15  = lane & 15;
    const int g    = lane >> 4;
    const long bh  = blockIdx.x;

    // ---- stage Q [256][64] ----
    const unsigned short* Qb = Qg + bh * 256 * 64;
    #pragma unroll
    for (int it = 0; it < 8; ++it) {
        const int row = it * 32 + (tid >> 3), s = tid & 7;
        uint4 d = *(const uint4*)(Qb + row * 64 + s * 8);
        *(uint4*)(Qs + row * QST + s * 8) = d;
    }
    __syncthreads();

    // hoist Q fragments to registers
    short8 qf[4][2];
    #pragma unroll
    for (int mt = 0; mt < 4; ++mt)
        #pragma unroll
        for (int kt = 0; kt < 2; ++kt)
            qf[mt][kt] = *(const short8*)(Qs +
                (wv * 64 + mt * 16 + l15) * QST + (kt * 4 + g) * 8);

    f32x4 po[4][4];
    float mrun[4][4], lrun[4][4];
    #pragma unroll
    for (int mt = 0; mt < 4; ++mt) {
        #pragma unroll
        for (int nt = 0; nt < 4; ++nt) po[mt][nt] = (f32x4){0.f,0.f,0.f,0.f};
        #pragma unroll
        for (int r = 0; r < 4; ++r) { mrun[mt][r] = -3.0e38f; lrun[mt][r] = 0.f; }
    }

    unsigned short* Pw = &Ps[wv][0];

    for (int t0 = 0; t0 < 256; t0 += 32) {
        __syncthreads();
        {   // stage K tile [32][64]
            const int u = tid >> 3, s = tid & 7;
            uint4 d = *(const uint4*)(Kg + (bh * 256 + t0 + u) * 64 + s * 8);
            *(uint4*)(Ks + u * QST + s * 8) = d;
        }
        {   // stage Vt tile [64 f][32 u]
            const int f = tid >> 2, c4 = tid & 3;
            uint4 d = *(const uint4*)(Vtg + (bh * 64 + f) * 256 + t0 + c4 * 8);
            *(uint4*)(Vts + f * PST + c4 * 8) = d;
        }
        __syncthreads();

        // ---- QK^T: S[64 w][32 kv] per wave ----
        f32x4 s[4][2];
        #pragma unroll
        for (int mt = 0; mt < 4; ++mt)
            #pragma unroll
            for (int nt = 0; nt < 2; ++nt) s[mt][nt] = (f32x4){0.f,0.f,0.f,0.f};
        #pragma unroll
        for (int kt = 0; kt < 2; ++kt) {
            #pragma unroll
            for (int nt = 0; nt < 2; ++nt) {
                const int kv = nt * 16 + l15;
                short8 kb = *(const short8*)(Ks + kv * QST + (kt * 4 + g) * 8);
                #pragma unroll
                for (int mt = 0; mt < 4; ++mt)
                    s[mt][nt] = mfma16(qf[mt][kt], kb, s[mt][nt]);
            }
        }

        // ---- online softmax ----
        #pragma unroll
        for (int mt = 0; mt < 4; ++mt) {
            #pragma unroll
            for (int r = 0; r < 4; ++r) {
                float t = fmaxf(s[mt][0][r], s[mt][1][r]);
                t = fmaxf(t, __shfl_xor(t, 1));
                t = fmaxf(t, __shfl_xor(t, 2));
                t = fmaxf(t, __shfl_xor(t, 4));
                t = fmaxf(t, __shfl_xor(t, 8));
                const float mo = mrun[mt][r];
                const float mn = fmaxf(mo, t);
                const float al = __expf(mo - mn);
                mrun[mt][r] = mn;
                const float p0 = __expf(s[mt][0][r] - mn);
                const float p1 = __expf(s[mt][1][r] - mn);
                float ss = p0 + p1;
                ss += __shfl_xor(ss, 1);
                ss += __shfl_xor(ss, 2);
                ss += __shfl_xor(ss, 4);
                ss += __shfl_xor(ss, 8);
                lrun[mt][r] = lrun[mt][r] * al + ss;
                #pragma unroll
                for (int nf = 0; nf < 4; ++nf) po[mt][nf][r] *= al;
                const int wrow = mt * 16 + 4 * g + r;
                Pw[wrow * PST + l15]      = f2h(p0);
                Pw[wrow * PST + 16 + l15] = f2h(p1);
            }
        }

        // ---- PV: O += P[64][32] * V[32][64] ----
        short8 vb[4];
        #pragma unroll
        for (int nf = 0; nf < 4; ++nf)
            vb[nf] = *(const short8*)(Vts + (nf * 16 + l15) * PST + g * 8);
        #pragma unroll
        for (int mt = 0; mt < 4; ++mt) {
            short8 pa = *(const short8*)(Pw + (mt * 16 + l15) * PST + g * 8);
            #pragma unroll
            for (int nf = 0; nf < 4; ++nf)
                po[mt][nf] = mfma16(pa, vb[nf], po[mt][nf]);
        }
    }

    // ---- epilogue ----
    #pragma unroll
    for (int mt = 0; mt < 4; ++mt) {
        #pragma unroll
        for (int r = 0; r < 4; ++r) {
            const float inv = 1.0f / lrun[mt][r];
            const long wrow = bh * 256 + wv * 64 + mt * 16 + 4 * g + r;
            #pragma unroll
            for (int nf = 0; nf < 4; ++nf)
                Out[wrow * 64 + nf * 16 + l15] = po[mt][nf][r] * inv;
        }
    }
}

extern "C" void kernel_launch(void* const* d_in, const int* in_sizes, int n_in,
                              void* d_out, int out_size, void* d_ws, size_t ws_size,
                              hipStream_t stream) {
    const float* X  = (const float*)d_in[0];
    const float* Wq = (const float*)d_in[1];
    const float* bq = (const float*)d_in[2];
    const float* Wk = (const float*)d_in[3];
    const float* bk = (const float*)d_in[4];
    const float* Wv = (const float*)d_in[5];
    const float* bv = (const float*)d_in[6];
    float* out = (float*)d_out;

    const size_t NE = (size_t)B_ * H_ * W_ * F_;      // 16,777,216
    unsigned short* q  = (unsigned short*)d_ws;
    unsigned short* k  = q + NE;
    unsigned short* vt = k + NE;
    unsigned short* wt = vt + NE;                      // 110592 shorts

    wprep_kernel<<<432, 256, 0, stream>>>(Wq, Wk, Wv, wt);
    conv_mfma<<<B_ * H_ * 2, 256, 0, stream>>>(X, wt, bq, bk, bv, q, k, vt);
    attn_mfma<<<B_ * H_, 256, 0, stream>>>(q, k, vt, out);
}

// Round 8
// 336.196 us; speedup vs baseline: 13.7706x; 1.0242x over previous
//
#include <hip/hip_runtime.h>

#define B_ 8
#define H_ 128
#define W_ 256
#define C_ 64
#define F_ 64

typedef __attribute__((ext_vector_type(8))) short short8;
typedef __attribute__((ext_vector_type(8))) _Float16 half8;
typedef __attribute__((ext_vector_type(4))) float f32x4;

__device__ __forceinline__ unsigned short f2h(float x) {
    _Float16 h = (_Float16)x;                  // v_cvt_f16_f32, RTN
    return __builtin_bit_cast(unsigned short, h);
}

__device__ __forceinline__ f32x4 mfma16(short8 a, short8 b, f32x4 c) {
    return __builtin_amdgcn_mfma_f32_16x16x32_f16(
        __builtin_bit_cast(half8, a), __builtin_bit_cast(half8, b), c, 0, 0, 0);
}

// ---------------------------------------------------------------------------
// Pre-kernel: transpose+convert weights to fp16  Wt[tap(9)][f(192)][c(64)].
// ---------------------------------------------------------------------------
__global__ void wprep_kernel(const float* __restrict__ Wq,
                             const float* __restrict__ Wk,
                             const float* __restrict__ Wv,
                             unsigned short* __restrict__ Wt)
{
    int e = blockIdx.x * 256 + threadIdx.x;           // < 110592
    int c   = e & 63;
    int f   = (e >> 6) % 192;
    int tap = e / 12288;
    const float* src = (f < 64) ? Wq : (f < 128) ? Wk : Wv;
    int ff = f & 63;
    float v = src[(long)tap * 4096 + c * 64 + ff];    // W[tap][c][F]
    Wt[e] = f2h(v);
}

// ---------------------------------------------------------------------------
// Fused q/k/v dilated 3x3 conv (dil=2, SAME) via fp16 MFMA.
// Grid: 1024 (b,h) x 2 f-halves (96 f). 256 thr = 4 waves, wave owns 64 w.
// K split into c-chunks of 32 (one MFMA K-step). LDS 39.5 KB -> 3-4 blk/CU.
// Outputs: Q,K fp16 [bh][w][f], V fp16 [bh][f][w] (f-major).
// ---------------------------------------------------------------------------
#define XST 36   // Xs row stride in shorts (72 B)
#define WST 36   // Wls row stride

__global__ __launch_bounds__(256, 3) void conv_mfma(
    const float* __restrict__ X, const unsigned short* __restrict__ Wt,
    const float* __restrict__ bq, const float* __restrict__ bk,
    const float* __restrict__ bv,
    unsigned short* __restrict__ Qg, unsigned short* __restrict__ Kg,
    unsigned short* __restrict__ Vtg)
{
    __shared__ __align__(16) unsigned short Xs[260 * XST];   // [w+2][c 32]
    __shared__ __align__(16) unsigned short Wls[288 * WST];  // [kw*96+f][c 32]

    const int tid  = threadIdx.x;
    const int wv   = tid >> 6;
    const int lane = tid & 63;
    const int l15  = lane & 15;
    const int g    = lane >> 4;
    const int bx   = blockIdx.x;
    const int bh   = bx >> 1;
    const int half = bx & 1;
    const int b    = bh >> 7;
    const int h    = bh & 127;

    f32x4 acc[4][6];
    #pragma unroll
    for (int mt = 0; mt < 4; ++mt)
        #pragma unroll
        for (int nt = 0; nt < 6; ++nt)
            acc[mt][nt] = (f32x4){0.f, 0.f, 0.f, 0.f};

    for (int kh = 0; kh < 3; ++kh) {
        const int ih = h + 2 * (kh - 1);
        if ((unsigned)ih >= (unsigned)H_) continue;     // block-uniform
        const float* Xr = X + ((long)(b * H_ + ih) * W_) * C_;

        for (int cc = 0; cc < 2; ++cc) {
            const int c0 = cc * 32;
            __syncthreads();   // protect previous phase's reads

            // ---- stage X: rows 0..259 = w -2..257, 32 channels ----
            for (int e = tid; e < 260 * 8; e += 256) {
                const int row = e >> 3, c4 = e & 7;
                const int w_in = row - 2;
                float4 val = make_float4(0.f, 0.f, 0.f, 0.f);
                if ((unsigned)w_in < (unsigned)W_)
                    val = *(const float4*)(Xr + (long)w_in * 64 + c0 + c4 * 4);
                uint2 p;
                p.x = (unsigned)f2h(val.x) | ((unsigned)f2h(val.y) << 16);
                p.y = (unsigned)f2h(val.z) | ((unsigned)f2h(val.w) << 16);
                *(uint2*)(Xs + row * XST + c4 * 4) = p;
            }
            // ---- stage weights: [kw][f 96][c 32] ----
            for (int e = tid; e < 1152; e += 256) {
                const int c8 = e & 3, f = (e >> 2) % 96, kw = e / 384;
                uint4 d = *(const uint4*)(Wt +
                    (((long)(kh * 3 + kw) * 192 + half * 96 + f) * 64 + c0 + c8 * 8));
                *(uint4*)(Wls + (kw * 96 + f) * WST + c8 * 8) = d;
            }
            __syncthreads();

            #pragma unroll
            for (int kw = 0; kw < 3; ++kw) {
                short8 bfrag[6];
                #pragma unroll
                for (int nt = 0; nt < 6; ++nt)
                    bfrag[nt] = *(const short8*)(Wls +
                        (kw * 96 + nt * 16 + l15) * WST + g * 8);
                #pragma unroll
                for (int mt = 0; mt < 4; ++mt) {
                    const int row = wv * 64 + mt * 16 + l15 + 2 * kw;
                    short8 a = *(const short8*)(Xs + row * XST + g * 8);
                    #pragma unroll
                    for (int nt = 0; nt < 6; ++nt)
                        acc[mt][nt] = mfma16(a, bfrag[nt], acc[mt][nt]);
                }
            }
        }
    }

    // ---- epilogue: bias + store fp16 ----
    float bias[6];
    #pragma unroll
    for (int nt = 0; nt < 6; ++nt) {
        const int fp = half * 96 + nt * 16 + l15;
        bias[nt] = (fp < 64) ? bq[fp] : (fp < 128) ? bk[fp - 64] : bv[fp - 128];
    }
    #pragma unroll
    for (int mt = 0; mt < 4; ++mt) {
        const int wrow = wv * 64 + mt * 16 + 4 * g;
        #pragma unroll
        for (int nt = 0; nt < 6; ++nt) {
            const int fp = half * 96 + nt * 16 + l15;
            if (fp < 128) {   // Q or K: [bh][w][f]
                unsigned short* dst = (fp < 64) ? Qg : Kg;
                const int f = fp & 63;
                #pragma unroll
                for (int r = 0; r < 4; ++r)
                    dst[((long)bh * 256 + wrow + r) * 64 + f] =
                        f2h(acc[mt][nt][r] + bias[nt]);
            } else {          // V transposed: [bh][f][w]
                const int f = fp - 128;
                uint2 p;
                p.x = (unsigned)f2h(acc[mt][nt][0] + bias[nt]) |
                      ((unsigned)f2h(acc[mt][nt][1] + bias[nt]) << 16);
                p.y = (unsigned)f2h(acc[mt][nt][2] + bias[nt]) |
                      ((unsigned)f2h(acc[mt][nt][3] + bias[nt]) << 16);
                *(uint2*)(Vtg + ((long)bh * 64 + f) * 256 + wrow) = p;
            }
        }
    }
}

// ---------------------------------------------------------------------------
// Flash attention per (b,h) via fp16 MFMA. 256 thr = 4 waves, wave owns 64
// q-rows. Q direct global->reg. KV tiles of 64, double-buffered (1 barrier
// per tile). Softmax denominator via ones-column MFMA; defer-max (THR=8).
// ---------------------------------------------------------------------------
#define KST 72   // Ks/Vts row stride (shorts)
#define PST 72   // Ps row stride

__global__ __launch_bounds__(256, 2) void attn_mfma(
    const unsigned short* __restrict__ Qg, const unsigned short* __restrict__ Kg,
    const unsigned short* __restrict__ Vtg, float* __restrict__ Out)
{
    __shared__ __align__(16) unsigned short Ks[2][64 * KST];
    __shared__ __align__(16) unsigned short Vts[2][64 * KST];
    __shared__ __align__(16) unsigned short Ps[4][64 * PST];

    const int tid  = threadIdx.x;
    const int wv   = tid >> 6;
    const int lane = tid & 63;
    const int l15  = lane & 15;
    const int g    = lane >> 4;
    const long bh  = blockIdx.x;

    // ---- Q fragments direct from global ----
    short8 qf[4][2];
    #pragma unroll
    for (int mt = 0; mt < 4; ++mt)
        #pragma unroll
        for (int kt = 0; kt < 2; ++kt)
            qf[mt][kt] = *(const short8*)(Qg +
                (bh * 256 + wv * 64 + mt * 16 + l15) * 64 + (kt * 4 + g) * 8);

    // stage helper indices: row = tid>>2 (64 rows), ch = (tid&3)*16
    const int srow = tid >> 2, sch = (tid & 3) * 16;

    // ---- prologue: stage tile 0 into buf 0 ----
    {
        const unsigned short* kp = Kg + (bh * 256 + srow) * 64 + sch;
        const unsigned short* vp = Vtg + (bh * 64 + srow) * 256 + sch;
        *(uint4*)(Ks[0] + srow * KST + sch)     = *(const uint4*)(kp);
        *(uint4*)(Ks[0] + srow * KST + sch + 8) = *(const uint4*)(kp + 8);
        *(uint4*)(Vts[0] + srow * KST + sch)     = *(const uint4*)(vp);
        *(uint4*)(Vts[0] + srow * KST + sch + 8) = *(const uint4*)(vp + 8);
    }

    f32x4 po[4][4], lacc[4];
    float mrun[4][4];
    #pragma unroll
    for (int mt = 0; mt < 4; ++mt) {
        #pragma unroll
        for (int nt = 0; nt < 4; ++nt) po[mt][nt] = (f32x4){0.f,0.f,0.f,0.f};
        lacc[mt] = (f32x4){0.f,0.f,0.f,0.f};
        #pragma unroll
        for (int r = 0; r < 4; ++r) mrun[mt][r] = -3.0e38f;
    }

    short8 ones;
    #pragma unroll
    for (int i = 0; i < 8; ++i) ones[i] = (short)0x3C00;   // fp16 1.0

    unsigned short* Pw = &Ps[wv][0];

    for (int t = 0; t < 4; ++t) {
        __syncthreads();            // buf[t&1] ready; prev reads of buf[t^1] done
        const int cur = t & 1;
        if (t < 3) {                // stage next tile into other buffer
            const int nx = cur ^ 1, t0 = (t + 1) * 64;
            const unsigned short* kp = Kg + (bh * 256 + t0 + srow) * 64 + sch;
            const unsigned short* vp = Vtg + (bh * 64 + srow) * 256 + t0 + sch;
            *(uint4*)(Ks[nx] + srow * KST + sch)     = *(const uint4*)(kp);
            *(uint4*)(Ks[nx] + srow * KST + sch + 8) = *(const uint4*)(kp + 8);
            *(uint4*)(Vts[nx] + srow * KST + sch)     = *(const uint4*)(vp);
            *(uint4*)(Vts[nx] + srow * KST + sch + 8) = *(const uint4*)(vp + 8);
        }

        // ---- QK^T: S[64 w][64 kv] per wave ----
        f32x4 s[4][4];
        #pragma unroll
        for (int mt = 0; mt < 4; ++mt)
            #pragma unroll
            for (int nt = 0; nt < 4; ++nt) s[mt][nt] = (f32x4){0.f,0.f,0.f,0.f};
        #pragma unroll
        for (int kt = 0; kt < 2; ++kt)
            #pragma unroll
            for (int nt = 0; nt < 4; ++nt) {
                short8 kb = *(const short8*)(Ks[cur] +
                    (nt * 16 + l15) * KST + (kt * 4 + g) * 8);
                #pragma unroll
                for (int mt = 0; mt < 4; ++mt)
                    s[mt][nt] = mfma16(qf[mt][kt], kb, s[mt][nt]);
            }

        // ---- online softmax (defer-max THR=8), P -> LDS ----
        #pragma unroll
        for (int mt = 0; mt < 4; ++mt) {
            float tm[4];
            #pragma unroll
            for (int r = 0; r < 4; ++r) {
                float a0 = fmaxf(s[mt][0][r], s[mt][1][r]);
                float a1 = fmaxf(s[mt][2][r], s[mt][3][r]);
                float t0 = fmaxf(a0, a1);
                t0 = fmaxf(t0, __shfl_xor(t0, 1));
                t0 = fmaxf(t0, __shfl_xor(t0, 2));
                t0 = fmaxf(t0, __shfl_xor(t0, 4));
                t0 = fmaxf(t0, __shfl_xor(t0, 8));
                tm[r] = t0;
            }
            float worst = tm[0] - mrun[mt][0];
            #pragma unroll
            for (int r = 1; r < 4; ++r) worst = fmaxf(worst, tm[r] - mrun[mt][r]);
            if (__all(worst <= 8.f)) {          // defer: keep old max
                #pragma unroll
                for (int r = 0; r < 4; ++r) {
                    const float mo = mrun[mt][r];
                    const int wrow = mt * 16 + 4 * g + r;
                    #pragma unroll
                    for (int nt = 0; nt < 4; ++nt)
                        Pw[wrow * PST + nt * 16 + l15] = f2h(__expf(s[mt][nt][r] - mo));
                }
            } else {
                #pragma unroll
                for (int r = 0; r < 4; ++r) {
                    const float mo = mrun[mt][r];
                    const float mn = fmaxf(mo, tm[r]);
                    const float al = __expf(mo - mn);
                    mrun[mt][r] = mn;
                    lacc[mt][r] *= al;
                    #pragma unroll
                    for (int nf = 0; nf < 4; ++nf) po[mt][nf][r] *= al;
                    const int wrow = mt * 16 + 4 * g + r;
                    #pragma unroll
                    for (int nt = 0; nt < 4; ++nt)
                        Pw[wrow * PST + nt * 16 + l15] = f2h(__expf(s[mt][nt][r] - mn));
                }
            }
        }

        // ---- PV: O += P[64][64] x V[64][64]; l += P row-sums (ones MFMA) ----
        #pragma unroll
        for (int kt = 0; kt < 2; ++kt) {
            short8 vb[4];
            #pragma unroll
            for (int nf = 0; nf < 4; ++nf)
                vb[nf] = *(const short8*)(Vts[cur] +
                    (nf * 16 + l15) * KST + (kt * 4 + g) * 8);
            #pragma unroll
            for (int mt = 0; mt < 4; ++mt) {
                short8 pa = *(const short8*)(Pw +
                    (mt * 16 + l15) * PST + (kt * 4 + g) * 8);
                #pragma unroll
                for (int nf = 0; nf < 4; ++nf)
                    po[mt][nf] = mfma16(pa, vb[nf], po[mt][nf]);
                lacc[mt] = mfma16(pa, ones, lacc[mt]);
            }
        }
    }

    // ---- epilogue ----
    #pragma unroll
    for (int mt = 0; mt < 4; ++mt) {
        #pragma unroll
        for (int r = 0; r < 4; ++r) {
            const float inv = 1.0f / lacc[mt][r];
            const long wrow = bh * 256 + wv * 64 + mt * 16 + 4 * g + r;
            #pragma unroll
            for (int nf = 0; nf < 4; ++nf)
                Out[wrow * 64 + nf * 16 + l15] = po[mt][nf][r] * inv;
        }
    }
}

extern "C" void kernel_launch(void* const* d_in, const int* in_sizes, int n_in,
                              void* d_out, int out_size, void* d_ws, size_t ws_size,
                              hipStream_t stream) {
    const float* X  = (const float*)d_in[0];
    const float* Wq = (const float*)d_in[1];
    const float* bq = (const float*)d_in[2];
    const float* Wk = (const float*)d_in[3];
    const float* bk = (const float*)d_in[4];
    const float* Wv = (const float*)d_in[5];
    const float* bv = (const float*)d_in[6];
    float* out = (float*)d_out;

    const size_t NE = (size_t)B_ * H_ * W_ * F_;      // 16,777,216
    unsigned short* q  = (unsigned short*)d_ws;
    unsigned short* k  = q + NE;
    unsigned short* vt = k + NE;
    unsigned short* wt = vt + NE;                      // 110592 shorts

    wprep_kernel<<<432, 256, 0, stream>>>(Wq, Wk, Wv, wt);
    conv_mfma<<<B_ * H_ * 2, 256, 0, stream>>>(X, wt, bq, bk, bv, q, k, vt);
    attn_mfma<<<B_ * H_, 256, 0, stream>>>(q, k, vt, out);
}